// Round 1
// 111.923 us; speedup vs baseline: 1.0054x; 1.0054x over previous
//
#include <hip/hip_runtime.h>
#include <math.h>

#define F 128
#define H 64        // hidden width of each MLP
#define ATILE 32    // atoms per MLP block (full H=64 per block)
#define NBMOL 48
#define CAP 256     // LDS chunk capacity in pair kernel
#define SPLIT 16    // blocks per molecule in pair kernel

__device__ __forceinline__ float silu_f(float x) {
    return x / (1.0f + __expf(-x));
}
__device__ __forceinline__ float softplus_f(float x) {
    return fmaxf(x, 0.0f) + log1pf(__expf(-fabsf(x)));
}
__device__ __forceinline__ float frcp(float x) {
    return __builtin_amdgcn_rcpf(x);
}
__device__ __forceinline__ float dot4(float4 a, float4 b) {
    return fmaf(a.x, b.x, fmaf(a.y, b.y, fmaf(a.z, b.z, a.w * b.w)));
}

// Fused per-atom kernel. Block roles by blockIdx.x:
//   [0, nmlp)           : MLP blocks. b -> (tile = b>>1, net = b&1).
//                         32 atoms x full H=64 hidden per block, so each
//                         h0 tile is fetched by only 2 blocks (was 4) and
//                         the MLP head (b2 / softplus / sqrt) finalizes
//                         here instead of in k_pair.
//                         LDS: W 32KB + X 16KB, XOR-swizzled, 3 blocks/CU.
//   [nmlp, nmlp+ndip)   : dipole blocks: 64 h1 rows each (4 per 16-lane
//                         slot), coalesced float4 dot with muW (hoisted to
//                         regs), 16-lane shuffle reduce.
//   last block          : segment boundaries from sorted batch + out[0]=0.
__global__ __launch_bounds__(256, 4) void k_atom(
    const float* __restrict__ h0, const float* __restrict__ h1,
    const int* __restrict__ batch,
    const float* __restrict__ qW1, const float* __restrict__ qb1,
    const float* __restrict__ qW2, const float* __restrict__ qb2,
    const float* __restrict__ cW1, const float* __restrict__ cb1,
    const float* __restrict__ cW2, const float* __restrict__ cb2,
    const float* __restrict__ muW,
    float* __restrict__ qout,      // plane of N: q incl. qb2
    float* __restrict__ sqc6,      // plane of N: sqrt(softplus(c6raw+cb2))
    float* __restrict__ mu,
    int* __restrict__ segstart, int* __restrict__ segend,
    float* __restrict__ out, int N, int nmlp, int ndip)
{
    __shared__ float4 sW4[H * 32];      // 32 KB, row h: f4 index XOR (h>>1)&7
    __shared__ float4 sX4[ATILE * 32];  // 16 KB, row a: f4 index XOR (a>>2)&7
    __shared__ float red[4][ATILE];     // 512 B epilogue reduce

    const int b = blockIdx.x;
    const int tid = threadIdx.x;

    if (b < nmlp) {
        const int tile = b >> 1;
        const int net  = b & 1;
        const float* __restrict__ W1 = net ? cW1 : qW1;
        const float* __restrict__ b1 = net ? cb1 : qb1;
        const float* __restrict__ W2 = net ? cW2 : qW2;

        // ---- stage weights (64 h x 128 f), transposed+swizzled ----
        // W1 layout is [f][h] row-major, so idx = f*64 + h is coalesced.
        for (int idx = tid; idx < H * F; idx += 256) {
            int f = idx >> 6, h = idx & 63;
            float val = W1[idx];
            int f4 = f >> 2, fi = f & 3;
            ((float*)&sW4[h * 32 + (f4 ^ ((h >> 1) & 7))])[fi] = val;
        }
        // ---- stage h0 tile (32 atoms x 128 f), swizzled, coalesced ----
        const float4* __restrict__ h0v = (const float4*)h0;
        for (int idx = tid; idx < ATILE * 32; idx += 256) {
            int a = idx >> 5, f4 = idx & 31;
            int row = min(tile * ATILE + a, N - 1);
            sX4[a * 32 + (f4 ^ ((a >> 2) & 7))] = h0v[(size_t)row * 32 + f4];
        }
        __syncthreads();

        // ---- compute: thread = (ag 0..7, hg 0..31) -> 4 atoms x 2 h ----
        const int ag = tid & 7;
        const int hg = tid >> 3;
        const int swx = ag;            // = ((4*ag+j)>>2)&7 for j=0..3
        const int sww = hg & 7;        // = ((2*hg)>>1)&7
        const int h0i = 2 * hg;

        float z[4][2];
        {
            float c0 = b1[h0i], c1 = b1[h0i + 1];
            #pragma unroll
            for (int j = 0; j < 4; ++j) { z[j][0] = c0; z[j][1] = c1; }
        }

        #pragma unroll 4
        for (int f4 = 0; f4 < 32; ++f4) {
            float4 w0 = sW4[h0i * 32 + (f4 ^ sww)];
            float4 w1 = sW4[(h0i + 1) * 32 + (f4 ^ sww)];
            #pragma unroll
            for (int j = 0; j < 4; ++j) {
                float4 x = sX4[(4 * ag + j) * 32 + (f4 ^ swx)];
                z[j][0] += dot4(x, w0);
                z[j][1] += dot4(x, w1);
            }
        }

        const float w2a = W2[h0i], w2b = W2[h0i + 1];
        float p[4];
        #pragma unroll
        for (int j = 0; j < 4; ++j)
            p[j] = fmaf(silu_f(z[j][0]), w2a, silu_f(z[j][1]) * w2b);

        // reduce over hg: bits 3,4,5 of tid in-wave; 4 waves via LDS
        #pragma unroll
        for (int j = 0; j < 4; ++j) {
            p[j] += __shfl_xor(p[j], 8);
            p[j] += __shfl_xor(p[j], 16);
            p[j] += __shfl_xor(p[j], 32);
        }
        const int wv = tid >> 6, lane = tid & 63;
        if (lane < 8) {
            #pragma unroll
            for (int j = 0; j < 4; ++j) red[wv][4 * lane + j] = p[j];
        }
        __syncthreads();
        if (tid < ATILE) {
            float s = red[0][tid] + red[1][tid] + red[2][tid] + red[3][tid];
            int atom = tile * ATILE + tid;
            if (atom < N) {
                if (net == 0) qout[atom] = s + qb2[0];
                else          sqc6[atom] = sqrtf(softplus_f(s + cb2[0]));
            }
        }
    } else if (b < nmlp + ndip) {
        // ---- dipole: 64 h1 rows per block, 16-lane slot, 4 rows/slot ----
        const int slot = tid >> 4;
        const int l = tid & 15;
        const float4* mp = (const float4*)muW;
        const float4 m0 = mp[2 * l];
        const float4 m1 = mp[2 * l + 1];
        const int base = (b - nmlp) * 64;
        #pragma unroll
        for (int rr = 0; rr < 4; ++rr) {
            int row = base + slot + 16 * rr;
            if (row < 3 * N) {
                const float4* rp = (const float4*)(h1 + (size_t)row * F);
                float pm = dot4(rp[2 * l], m0) + dot4(rp[2 * l + 1], m1);
                #pragma unroll
                for (int off = 1; off < 16; off <<= 1) pm += __shfl_xor(pm, off);
                if (l == 0) mu[row] = pm;
            }
        }
    } else {
        // ---- segment boundaries + out zero ----
        if (tid == 0) out[0] = 0.0f;
        for (int i = tid; i < N; i += 256) {
            int bb = batch[i];
            if (i == 0 || batch[i - 1] != bb) segstart[bb] = i;
            if (i == N - 1 || batch[i + 1] != bb) segend[bb] = i + 1;
        }
    }
}

// Pairwise energy. Grid (NBMOL, SPLIT); block 256. Per-atom quantities are
// fully finalized by k_atom; q is mean-centered in LDS once (not per pair).
__global__ __launch_bounds__(256) void k_pair(
    const float* __restrict__ pos,
    const float* __restrict__ qg,     // N: q incl. qb2
    const float* __restrict__ cg,     // N: sqrt(softplus(c6))
    const float* __restrict__ mu,
    const int* __restrict__ segstart, const int* __restrict__ segend,
    float* __restrict__ out, int N)
{
    const int b = blockIdx.x;
    const int s = blockIdx.y;
    const int tid = threadIdx.x;
    const int st = segstart[b];
    const int n = segend[b] - st;

    __shared__ float sq[CAP], sc[CAP], sp[3 * CAP], sm[3 * CAP];
    __shared__ float red[4];

    float e_c = 0.f, e_v = 0.f, e_d = 0.f;

    if (n > 1 && n <= CAP) {
        float partsum = 0.f;
        for (int k = tid; k < n; k += 256) {
            float qv = qg[st + k];
            sq[k] = qv; partsum += qv;
            sc[k] = cg[st + k];
        }
        for (int k = tid; k < 3 * n; k += 256) {
            sp[k] = pos[3 * st + k];
            sm[k] = mu[3 * st + k];
        }
        #pragma unroll
        for (int off = 32; off > 0; off >>= 1)
            partsum += __shfl_xor(partsum, off);
        if ((tid & 63) == 0) red[tid >> 6] = partsum;
        __syncthreads();
        const float mean = (red[0] + red[1] + red[2] + red[3]) / (float)n;
        for (int k = tid; k < n; k += 256) sq[k] -= mean;  // center once
        __syncthreads();

        const int r = tid >> 4;
        const int c = tid & 15;
        for (int il = s + SPLIT * r; il < n; il += SPLIT * 16) {
            const float qi = sq[il];
            const float sci = sc[il];
            const float xi = sp[3 * il], yi = sp[3 * il + 1], zi = sp[3 * il + 2];
            const float mxi = sm[3 * il], myi = sm[3 * il + 1], mzi = sm[3 * il + 2];
            for (int jl = c; jl < n; jl += 16) {
                if (jl == il) continue;
                float dx = xi - sp[3 * jl], dy = yi - sp[3 * jl + 1],
                      dz = zi - sp[3 * jl + 2];
                float ds0 = fmaf(dx, dx, fmaf(dy, dy, dz * dz));
                float d = sqrtf(ds0 + 1e-8f);
                float inv_d = frcp(d);
                float qj = sq[jl];
                e_c = fmaf(qi * qj * inv_d, 1.0f - __expf(-0.5f * d), e_c);
                float r6 = ds0 * ds0 * ds0;
                e_v = fmaf(sci * sc[jl], frcp(r6 + 20.0f), e_v);
                float smx = sm[3 * jl], smy = sm[3 * jl + 1], smz = sm[3 * jl + 2];
                float mdm = fmaf(mxi, smx, fmaf(myi, smy, mzi * smz));
                float mdni = fmaf(mxi, dx, fmaf(myi, dy, mzi * dz)) * inv_d;
                float mdnj = fmaf(smx, dx, fmaf(smy, dy, smz * dz)) * inv_d;
                e_d = fmaf(mdm - 3.0f * mdni * mdnj,
                           frcp(fmaf(ds0, d, 10.0f)), e_d);
            }
        }
    } else if (n > CAP) {
        // generic chunked fallback (not hit at N/NB ~128, kept for safety)
        float partsum = 0.f;
        for (int k = tid; k < n; k += 256)
            partsum += qg[st + k];
        #pragma unroll
        for (int off = 32; off > 0; off >>= 1)
            partsum += __shfl_xor(partsum, off);
        if ((tid & 63) == 0) red[tid >> 6] = partsum;
        __syncthreads();
        const float mean = (red[0] + red[1] + red[2] + red[3]) / (float)n;
        const int r = tid >> 4, c = tid & 15;
        for (int j0 = 0; j0 < n; j0 += CAP) {
            const int chunk = min(CAP, n - j0);
            __syncthreads();
            for (int k = tid; k < chunk; k += 256) {
                int j = st + j0 + k;
                sq[k] = qg[j] - mean;
                sc[k] = cg[j];
            }
            for (int k = tid; k < 3 * chunk; k += 256) {
                sp[k] = pos[3 * (st + j0) + k];
                sm[k] = mu[3 * (st + j0) + k];
            }
            __syncthreads();
            for (int il = s + SPLIT * r; il < n; il += SPLIT * 16) {
                const int i = st + il;
                const float qi = qg[i] - mean;
                const float sci = cg[i];
                const float xi = pos[i * 3], yi = pos[i * 3 + 1], zi = pos[i * 3 + 2];
                const float mxi = mu[i * 3], myi = mu[i * 3 + 1], mzi = mu[i * 3 + 2];
                for (int jl = c; jl < chunk; jl += 16) {
                    if (j0 + jl == il) continue;
                    float dx = xi - sp[3 * jl], dy = yi - sp[3 * jl + 1],
                          dz = zi - sp[3 * jl + 2];
                    float ds0 = fmaf(dx, dx, fmaf(dy, dy, dz * dz));
                    float d = sqrtf(ds0 + 1e-8f);
                    float inv_d = frcp(d);
                    float qj = sq[jl];
                    e_c = fmaf(qi * qj * inv_d, 1.0f - __expf(-0.5f * d), e_c);
                    float r6 = ds0 * ds0 * ds0;
                    e_v = fmaf(sci * sc[jl], frcp(r6 + 20.0f), e_v);
                    float smx = sm[3 * jl], smy = sm[3 * jl + 1], smz = sm[3 * jl + 2];
                    float mdm = fmaf(mxi, smx, fmaf(myi, smy, mzi * smz));
                    float mdni = fmaf(mxi, dx, fmaf(myi, dy, mzi * dz)) * inv_d;
                    float mdnj = fmaf(smx, dx, fmaf(smy, dy, smz * dz)) * inv_d;
                    e_d = fmaf(mdm - 3.0f * mdni * mdnj,
                               frcp(fmaf(ds0, d, 10.0f)), e_d);
                }
            }
        }
    }

    float vv = fmaf(7.1995f, e_c, fmaf(-0.5f, e_v, 0.5f * e_d));
    #pragma unroll
    for (int off = 32; off > 0; off >>= 1) vv += __shfl_xor(vv, off);
    __syncthreads();
    if ((tid & 63) == 0) red[tid >> 6] = vv;
    __syncthreads();
    if (tid == 0) atomicAdd(out, red[0] + red[1] + red[2] + red[3]);
}

extern "C" void kernel_launch(void* const* d_in, const int* in_sizes, int n_in,
                              void* d_out, int out_size, void* d_ws, size_t ws_size,
                              hipStream_t stream) {
    const float* h0  = (const float*)d_in[0];
    const float* h1  = (const float*)d_in[1];
    const float* pos = (const float*)d_in[2];
    const int*   batch = (const int*)d_in[3];
    const float* qW1 = (const float*)d_in[4];
    const float* qb1 = (const float*)d_in[5];
    const float* qW2 = (const float*)d_in[6];
    const float* qb2 = (const float*)d_in[7];
    const float* cW1 = (const float*)d_in[8];
    const float* cb1 = (const float*)d_in[9];
    const float* cW2 = (const float*)d_in[10];
    const float* cb2 = (const float*)d_in[11];
    const float* muW = (const float*)d_in[12];
    float* out = (float*)d_out;
    const int N = in_sizes[0] / F;

    // ws layout (floats): [segstart 48 | segend 48 | pad to 128 |
    //                      q N | sqc6 N | mu 3N]
    float* ws = (float*)d_ws;
    int* segstart = (int*)ws;
    int* segend   = (int*)(ws + 48);
    float* qplane = ws + 128;
    float* cplane = qplane + (size_t)N;
    float* mu     = cplane + (size_t)N;

    const int ntile = (N + ATILE - 1) / ATILE;
    const int nmlp = 2 * ntile;                 // 2 nets x full H per block
    const int ndip = (3 * N + 63) / 64;
    const int grid = nmlp + ndip + 1;

    k_atom<<<grid, 256, 0, stream>>>(h0, h1, batch,
                                     qW1, qb1, qW2, qb2,
                                     cW1, cb1, cW2, cb2, muW,
                                     qplane, cplane, mu, segstart, segend, out,
                                     N, nmlp, ndip);
    k_pair<<<dim3(NBMOL, SPLIT), 256, 0, stream>>>(pos, qplane, cplane, mu,
                                                   segstart, segend, out, N);
}